// Round 13
// baseline (126.850 us; speedup 1.0000x reference)
//
#include <hip/hip_runtime.h>
#include <hip/hip_bf16.h>
#include <cstdint>

// MultiHeadAttention fused pipeline for MI355X (gfx950).
// Phases: cvt(fp32->bf16, fused) -> QKV GEMM (2-phase dbuf, bias + scatter Q/K/V)
//         -> V transpose (LDS-tiled) -> flash attention (causal, 32x32 MFMA,
//            P in-register, dbuf LDS K/V) -> out-proj GEMM (dbuf).

#define DEV __device__ __forceinline__

#define VT_STRIDE 2048  // V^T row stride in elems

using bf16x8 = __attribute__((ext_vector_type(8))) short;
using f32x4  = __attribute__((ext_vector_type(4))) float;
using f32x16 = __attribute__((ext_vector_type(16))) float;
using u32x4  = __attribute__((ext_vector_type(4))) unsigned;

DEV unsigned short f2bf(float f) {
  unsigned u = __builtin_bit_cast(unsigned, f);
  u = (u + 0x7fffu + ((u >> 16) & 1u)) >> 16;  // RNE
  return (unsigned short)u;
}

typedef __attribute__((address_space(1))) unsigned int as1_uint;
typedef __attribute__((address_space(3))) unsigned int as3_uint;

// async global->LDS, 16B per lane. LDS dest must be uniform base + lane*16.
DEV void gload_lds16(const void* g, void* l) {
  __builtin_amdgcn_global_load_lds(
      (as1_uint*)(uintptr_t)g,
      (as3_uint*)(unsigned int)(uintptr_t)l,
      16, 0, 0);
}

// fused fp32->bf16 convert for x | W_qkv | W_out (one launch).
#define N4_X  (4096 * 1024 / 4)
#define N4_WQ (3072 * 1024 / 4)
#define N4_WO (1024 * 1024 / 4)
__global__ __launch_bounds__(256) void cvt_all_k(const float* __restrict__ x,
                                                 const float* __restrict__ wq,
                                                 const float* __restrict__ wo,
                                                 unsigned short* __restrict__ xb,
                                                 unsigned short* __restrict__ wqb,
                                                 unsigned short* __restrict__ wob) {
  int i = blockIdx.x * 256 + threadIdx.x;
  const float* in; unsigned short* out;
  if (i < N4_X)                { in = x;  out = xb; }
  else if (i < N4_X + N4_WQ)   { i -= N4_X;  in = wq; out = wqb; }
  else                         { i -= N4_X + N4_WQ; in = wo; out = wob; }
  float4 v = reinterpret_cast<const float4*>(in)[i];
  ushort4 o;
  o.x = f2bf(v.x); o.y = f2bf(v.y); o.z = f2bf(v.z); o.w = f2bf(v.w);
  reinterpret_cast<ushort4*>(out)[i] = o;
}

// V [bh, s, d] -> V^T [bh, d, s].  64x64 tiles through swizzled LDS,
// coalesced global reads AND writes.
__global__ __launch_bounds__(256) void transpose_v_k(const unsigned short* __restrict__ V,
                                                     unsigned short* __restrict__ Vt) {
  const int bh = blockIdx.x;   // 32
  const int st = blockIdx.y;   // 32 s-tiles of 64
  const int tid = threadIdx.x;
  __shared__ unsigned short T[64 * 64];  // 8 KB
  const unsigned short* src = V + ((size_t)bh * 2048 + st * 64) * 64;  // contiguous 8KB

#pragma unroll
  for (int it = 0; it < 2; ++it) {
    const int c = it * 256 + tid;
    const int L = c * 16;
    const int S = L ^ (((L >> 10) & 7) << 4);
    gload_lds16((const char*)src + S, (char*)T + L);
  }
  __syncthreads();

#pragma unroll
  for (int it = 0; it < 2; ++it) {
    const int c = it * 256 + tid;
    const int d = c >> 3;
    const int s_off = (c & 7) * 8;
    const int xg = (c & 7) << 4;
    bf16x8 pk;
#pragma unroll
    for (int j = 0; j < 8; ++j)
      pk[j] = *(const short*)((const char*)T + (((s_off + j) * 128 + d * 2) ^ xg));
    *(bf16x8*)(Vt + (size_t)(bh * 64 + d) * VT_STRIDE + st * 64 + s_off) = pk;
  }
}

// C[M,N] = A[M,K](bf16) * W[N,K](bf16)^T + bias.
// MODE 0: Cout fp32 [M,N].  MODE 1: scatter to Q/K/V, all [bh, s, d] bf16 (coalesced).
// 128x128 tile, BK=64, 4 waves (2x2), 16x16x32 bf16 MFMA.
// 2-PHASE PIPELINE: double-buffered LDS staged via global_load_lds; per K-step
// {STAGE(next) -> s_waitcnt vmcnt(8) -> s_barrier -> MFMA -> s_barrier}.
// T2 XOR-swizzle via pre-swizzled global source.
template <int MODE, int N, int K>
__global__ __launch_bounds__(256) void gemm_bt(const unsigned short* __restrict__ A,
                                               const unsigned short* __restrict__ W,
                                               const float* __restrict__ bias,
                                               float* __restrict__ Cout,
                                               unsigned short* __restrict__ Qp,
                                               unsigned short* __restrict__ Kp,
                                               unsigned short* __restrict__ Vp) {
  __shared__ unsigned short As[2][128 * 64];
  __shared__ unsigned short Bs[2][128 * 64];
  const int tid = threadIdx.x;
  const int m0 = blockIdx.x * 128;
  const int n0 = blockIdx.y * 128;
  const int w = tid >> 6, lane = tid & 63, g = lane >> 4, lr = lane & 15;
  const int wr = w >> 1, wc = w & 1;
  const int xr = (lr & 7) << 4;

  f32x4 acc[4][4];
#pragma unroll
  for (int i = 0; i < 4; ++i)
#pragma unroll
    for (int j = 0; j < 4; ++j)
#pragma unroll
      for (int r = 0; r < 4; ++r) acc[i][j][r] = 0.f;

#define GSTAGE(buf, kt)                                                                     \
  do {                                                                                      \
    _Pragma("unroll")                                                                       \
    for (int it = 0; it < 4; ++it) {                                                        \
      const int c = it * 256 + tid;                                                         \
      const int row = c >> 3;                                                               \
      const int colb = ((c & 7) * 16) ^ ((row & 7) << 4);                                   \
      gload_lds16((const char*)(A + (size_t)(m0 + row) * K + (kt)) + colb,                  \
                  (char*)As[buf] + c * 16);                                                 \
      gload_lds16((const char*)(W + (size_t)(n0 + row) * K + (kt)) + colb,                  \
                  (char*)Bs[buf] + c * 16);                                                 \
    }                                                                                       \
  } while (0)

  GSTAGE(0, 0);
  int cur = 0;
  const int nsteps = K / 64;
  for (int step = 0; step < nsteps; ++step) {
    if (step + 1 < nsteps) {
      GSTAGE(cur ^ 1, (step + 1) * 64);
      asm volatile("s_waitcnt vmcnt(8)" ::: "memory");  // own tile loads landed; 8 newest in flight
    } else {
      asm volatile("s_waitcnt vmcnt(0)" ::: "memory");
    }
    __builtin_amdgcn_s_barrier();   // all waves' current-tile loads landed
    __builtin_amdgcn_sched_barrier(0);

    const char* AsC = (const char*)As[cur];
    const char* BsC = (const char*)Bs[cur];
    __builtin_amdgcn_s_setprio(1);
#pragma unroll
    for (int ks = 0; ks < 2; ++ks) {
      bf16x8 af[4], bf[4];
#pragma unroll
      for (int mi = 0; mi < 4; ++mi)
        af[mi] = *(const bf16x8*)(AsC +
                   ((((wr * 64 + mi * 16 + lr) * 128) + ks * 64 + g * 16) ^ xr));
#pragma unroll
      for (int ni = 0; ni < 4; ++ni)
        bf[ni] = *(const bf16x8*)(BsC +
                   ((((wc * 64 + ni * 16 + lr) * 128) + ks * 64 + g * 16) ^ xr));
#pragma unroll
      for (int mi = 0; mi < 4; ++mi)
#pragma unroll
        for (int ni = 0; ni < 4; ++ni)
          acc[mi][ni] = __builtin_amdgcn_mfma_f32_16x16x32_bf16(af[mi], bf[ni], acc[mi][ni], 0, 0, 0);
    }
    __builtin_amdgcn_s_setprio(0);

    asm volatile("" ::: "memory");
    __builtin_amdgcn_s_barrier();   // all waves done reading buf[cur]
    __builtin_amdgcn_sched_barrier(0);
    cur ^= 1;
  }
#undef GSTAGE

  if (MODE == 0) {
#pragma unroll
    for (int ni = 0; ni < 4; ++ni) {
      const int col = n0 + wc * 64 + ni * 16 + lr;
      const float bv = bias[col];
#pragma unroll
      for (int mi = 0; mi < 4; ++mi)
#pragma unroll
        for (int r = 0; r < 4; ++r) {
          const int row = m0 + wr * 64 + mi * 16 + g * 4 + r;
          Cout[(size_t)row * N + col] = acc[mi][ni][r] + bv;
        }
    }
  } else {
#pragma unroll
    for (int ni = 0; ni < 4; ++ni) {
      const int col = n0 + wc * 64 + ni * 16 + lr;
      const float bv = bias[col];
      const int which = col >> 10;
      const int h = (col >> 6) & 15;
      const int d = col & 63;
      unsigned short* P = which == 0 ? Qp : which == 1 ? Kp : Vp;
#pragma unroll
      for (int mi = 0; mi < 4; ++mi)
#pragma unroll
        for (int r = 0; r < 4; ++r) {
          const int row = m0 + wr * 64 + mi * 16 + g * 4 + r;
          const int b = row >> 11, s = row & 2047;
          P[(((size_t)(b * 16 + h) * 2048 + s) << 6) + d] = f2bf(acc[mi][ni][r] + bv);
        }
    }
  }
}

// Flash attention, causal. grid (bh=32, qb=8), 256 threads = 4 waves.
// 32x32x16 MFMA; each wave owns 32 q-rows; block tile = 128 rows. Block runs
// TWO tiles (qt = qb, 15-qb) -> uniform 34 kv-iterations, 256 blocks = 1/CU.
// LDS-BW reduction vs 16x16 version: frags feed 2x FLOP, and P never touches
// LDS -- swapped QK^T leaves P[key][q=lane&31] in regs; cvt_pk + shfl_xor(32)
// cross-half exchange builds PV A-fragments in-register (T12, shfl variant).
// K/V 64x64 tiles double-buffered (global_load_lds, pre-swizzled source),
// counted vmcnt(4). No-max exp2 softmax; per-lane l partial; 1 shfl reduce.
__global__ __launch_bounds__(256) void attn_fwd(const unsigned short* __restrict__ Q,
                                                const unsigned short* __restrict__ Kg,
                                                const unsigned short* __restrict__ Vt,
                                                unsigned short* __restrict__ AO) {
  const int bh = blockIdx.x;            // b*16 + h
  const int qb = blockIdx.y;            // 0..7
  const int tid = threadIdx.x;
  const int w = tid >> 6, lane = tid & 63;
  const int l31 = lane & 31, hi = lane >> 5;
  const int xr = (lane & 7) << 4;
  const unsigned short* Qp = Q  + (size_t)bh * 2048 * 64;
  const unsigned short* Kp = Kg + (size_t)bh * 2048 * 64;
  const unsigned short* Vp = Vt + (size_t)bh * 64 * VT_STRIDE;
  const int b = bh >> 4, h = bh & 15;

  __shared__ unsigned short Ks[2][64 * 64];  // 16 KB dbuf K
  __shared__ unsigned short Vs[2][64 * 64];  // 16 KB dbuf V^T

  const float C = 0.1803368801f;  // 0.125 * log2(e)

  const int L0 = tid * 16,         L1 = (tid + 256) * 16;
  const int G0 = L0 ^ (((L0 >> 7) & 7) << 4);
  const int G1 = L1 ^ (((L1 >> 7) & 7) << 4);

#define STAGE(buf, kvb)                                                                     \
  do {                                                                                      \
    gload_lds16((const char*)Kp + (size_t)(kvb) * 128 + G0, (char*)Ks[buf] + L0);           \
    gload_lds16((const char*)Kp + (size_t)(kvb) * 128 + G1, (char*)Ks[buf] + L1);           \
    gload_lds16((const char*)Vp + (size_t)(G0 >> 7) * (VT_STRIDE * 2) + (size_t)(kvb) * 2 + \
                    (G0 & 127), (char*)Vs[buf] + L0);                                       \
    gload_lds16((const char*)Vp + (size_t)(G1 >> 7) * (VT_STRIDE * 2) + (size_t)(kvb) * 2 + \
                    (G1 & 127), (char*)Vs[buf] + L1);                                       \
  } while (0)

#pragma unroll
  for (int half = 0; half < 2; ++half) {
    const int qt = half ? (15 - qb) : qb;
    const int nb = 2 * qt + 2;             // kv blocks of 64 cover rows < 128*qt+128
    const int qrow0 = qt * 128 + w * 32;   // this wave's 32 q-rows

    STAGE(0, 0);
    int cur = 0;

    // Q as B-fragments: B[k=d][col=q=l31]; lane reads Q[qrow0+l31][ds*16+hi*8 .. +8]
    bf16x8 qf[4];
#pragma unroll
    for (int ds = 0; ds < 4; ++ds)
      qf[ds] = *(const bf16x8*)(Qp + (size_t)(qrow0 + l31) * 64 + ds * 16 + hi * 8);

    f32x16 o0, o1;       // O[q rows][d 0-31], [d 32-63]
#pragma unroll
    for (int r = 0; r < 16; ++r) { o0[r] = 0.f; o1[r] = 0.f; }
    float lp = 0.f;      // partial row-sum for q = l31 (keys this lane holds)

    for (int t = 0; t < nb; ++t) {
      const int kvb = t * 64;
      if (t + 1 < nb) {
        STAGE(cur ^ 1, (t + 1) * 64);
        asm volatile("s_waitcnt vmcnt(4)" ::: "memory");  // own tile-t loads landed
      } else {
        asm volatile("s_waitcnt vmcnt(0)" ::: "memory");
      }
      __builtin_amdgcn_s_barrier();        // all waves' tile-t loads landed
      __builtin_amdgcn_sched_barrier(0);

      const char* KsC = (const char*)Ks[cur];
      const char* VsC = (const char*)Vs[cur];

      // ---- QK^T SWAPPED (32x32x16): D[col=q=l31, row=key (reg,hi) layout] ----
      f32x16 s0, s1;     // key blocks 0-31, 32-63
#pragma unroll
      for (int r = 0; r < 16; ++r) { s0[r] = 0.f; s1[r] = 0.f; }
      __builtin_amdgcn_s_setprio(1);
#pragma unroll
      for (int ds = 0; ds < 4; ++ds) {
        bf16x8 k0 = *(const bf16x8*)(KsC + ((l31 * 128 + ds * 32 + hi * 16) ^ xr));
        bf16x8 k1 = *(const bf16x8*)(KsC + (((32 + l31) * 128 + ds * 32 + hi * 16) ^ xr));
        s0 = __builtin_amdgcn_mfma_f32_32x32x16_bf16(k0, qf[ds], s0, 0, 0, 0);
        s1 = __builtin_amdgcn_mfma_f32_32x32x16_bf16(k1, qf[ds], s1, 0, 0, 0);
      }
      __builtin_amdgcn_s_setprio(0);

      // ---- causal mask (last two kv blocks): key kvb+koff > q qrow0+l31 ----
      if (t >= nb - 2) {
        const int thr = qrow0 + l31 - kvb;
#pragma unroll
        for (int reg = 0; reg < 16; ++reg) {
          const int koff = (reg & 3) + 8 * (reg >> 2) + 4 * hi;
          if (koff > thr)      s0[reg] = -INFINITY;
          if (koff + 32 > thr) s1[reg] = -INFINITY;
        }
      }

      // ---- no-max softmax: p = exp2(s*C); per-lane partial sum ----
#pragma unroll
      for (int reg = 0; reg < 16; ++reg) {
        float a0 = exp2f(s0[reg] * C);
        float a1 = exp2f(s1[reg] * C);
        s0[reg] = a0; s1[reg] = a1;
        lp += a0 + a1;
      }

      // ---- pack P into PV A-frags (in-register; T12 shfl variant) ----
      // lane holds P[key=(reg&3)+8*(reg>>2)+4*hi][q=l31]; A-frag ks needs
      // P[q=l31][keys ks*16+hi*8+0..7]. words w_j = cvt_pk(p_2j, p_2j+1);
      // cross-half halves exchanged via shfl_xor(32) + select on hi.
      bf16x8 pa[4];
#pragma unroll
      for (int kb = 0; kb < 2; ++kb) {
        unsigned wv[8], tv[8];
#pragma unroll
        for (int j = 0; j < 8; ++j) {
          float e0 = kb ? s1[2 * j] : s0[2 * j];
          float e1 = kb ? s1[2 * j + 1] : s0[2 * j + 1];
          asm("v_cvt_pk_bf16_f32 %0, %1, %2" : "=v"(wv[j]) : "v"(e0), "v"(e1));
        }
#pragma unroll
        for (int j = 0; j < 8; ++j) tv[j] = (unsigned)__shfl_xor((int)wv[j], 32);
        u32x4 ua, ub;
        ua[0] = hi ? tv[2] : wv[0]; ua[1] = hi ? tv[3] : wv[1];
        ua[2] = hi ? wv[2] : tv[0]; ua[3] = hi ? wv[3] : tv[1];
        ub[0] = hi ? tv[6] : wv[4]; ub[1] = hi ? tv[7] : wv[5];
        ub[2] = hi ? wv[6] : tv[4]; ub[3] = hi ? wv[7] : tv[5];
        pa[kb * 2]     = __builtin_bit_cast(bf16x8, ua);
        pa[kb * 2 + 1] = __builtin_bit_cast(bf16x8, ub);
      }

      // ---- PV (32x32x16): O[q][d] += P[q][k] V[k][d] ----
      __builtin_amdgcn_s_setprio(1);
#pragma unroll
      for (int ks = 0; ks < 4; ++ks) {
        bf16x8 v0 = *(const bf16x8*)(VsC + ((l31 * 128 + ks * 32 + hi * 16) ^ xr));
        bf16x8 v1 = *(const bf16x8*)(VsC + (((32 + l31) * 128 + ks * 32 + hi * 16) ^ xr));
        o0 = __builtin_amdgcn_mfma_f32_32x32x16_bf16(pa[ks], v0, o0, 0, 0, 0);
        o1 = __builtin_amdgcn_mfma_f32_32x32x16_bf16(pa[ks], v1, o1, 0, 0, 0);
      }
      __builtin_amdgcn_s_setprio(0);

      asm volatile("" ::: "memory");
      __builtin_amdgcn_s_barrier();        // all waves done reading buf[cur]
      __builtin_amdgcn_sched_barrier(0);
      cur ^= 1;
    }

    // ---- finalize: l lives split across lanes l31 / l31+32; one xor-reduce ----
    lp += __shfl_xor(lp, 32);
    const float inv = 1.0f / lp;           // valid for q = l31 on every lane
#pragma unroll
    for (int reg = 0; reg < 16; ++reg) {
      const int qoff = (reg & 3) + 8 * (reg >> 2) + 4 * hi;
      const float li = __shfl(inv, qoff);  // inv for q-row qoff (lane qoff holds it)
      const int row = qrow0 + qoff;
      AO[(size_t)(b * 2048 + row) * 1024 + h * 64 + l31]      = f2bf(o0[reg] * li);
      AO[(size_t)(b * 2048 + row) * 1024 + h * 64 + 32 + l31] = f2bf(o1[reg] * li);
    }
  }
#undef STAGE
}

extern "C" void kernel_launch(void* const* d_in, const int* in_sizes, int n_in,
                              void* d_out, int out_size, void* d_ws, size_t ws_size,
                              hipStream_t stream) {
  const float* x     = (const float*)d_in[0];
  const float* W_qkv = (const float*)d_in[1];
  const float* b_qkv = (const float*)d_in[2];
  const float* W_out = (const float*)d_in[3];
  const float* b_out = (const float*)d_in[4];
  float* out = (float*)d_out;

  // workspace layout (48 MB exactly, fully rewritten every call)
  // AOb reuses xb's region: xb dead after QKV GEMM completes (stream-ordered).
  char* ws = (char*)d_ws;
  unsigned short* xb  = (unsigned short*)(ws);                      // 8 MB x bf16 [4096,1024]
  unsigned short* AOb = (unsigned short*)(ws);                      // 8 MB attn out (reuse)
  unsigned short* wqb = (unsigned short*)(ws + ((size_t)8 << 20));  // 6 MB W_qkv bf16
  unsigned short* wob = (unsigned short*)(ws + ((size_t)14 << 20)); // 2 MB W_out bf16
  unsigned short* Qb  = (unsigned short*)(ws + ((size_t)16 << 20)); // 8 MB Q [bh,s,d]
  unsigned short* Kb  = (unsigned short*)(ws + ((size_t)24 << 20)); // 8 MB K [bh,s,d]
  unsigned short* Vb  = (unsigned short*)(ws + ((size_t)32 << 20)); // 8 MB V [bh,s,d]
  unsigned short* Vtb = (unsigned short*)(ws + ((size_t)40 << 20)); // 8 MB V^T [bh,d,s]

  cvt_all_k<<<(N4_X + N4_WQ + N4_WO) / 256, 256, 0, stream>>>(x, W_qkv, W_out, xb, wqb, wob);

  gemm_bt<1, 3072, 1024><<<dim3(32, 24), 256, 0, stream>>>(xb, wqb, b_qkv, nullptr, Qb, Kb, Vb);
  transpose_v_k<<<dim3(32, 32), 256, 0, stream>>>(Vb, Vtb);
  attn_fwd<<<dim3(32, 8), 256, 0, stream>>>(Qb, Kb, Vtb, AOb);
  gemm_bt<0, 1024, 1024><<<dim3(32, 8), 256, 0, stream>>>(AOb, wob, b_out, out, nullptr, nullptr, nullptr);
}

// Round 14
// 123.651 us; speedup vs baseline: 1.0259x; 1.0259x over previous
//
#include <hip/hip_runtime.h>
#include <hip/hip_bf16.h>
#include <cstdint>

// MultiHeadAttention fused pipeline for MI355X (gfx950).
// Phases: cvt(fp32->bf16, fused) -> QKV GEMM (2-phase dbuf, bias + scatter Q/K/V)
//         -> V transpose (LDS-tiled) -> flash attention (causal, 32x32 MFMA,
//            P in-register, dbuf LDS K/V, 512 blocks LPT) -> out-proj GEMM (dbuf).

#define DEV __device__ __forceinline__

#define VT_STRIDE 2048  // V^T row stride in elems

using bf16x8 = __attribute__((ext_vector_type(8))) short;
using f32x4  = __attribute__((ext_vector_type(4))) float;
using f32x16 = __attribute__((ext_vector_type(16))) float;
using u32x4  = __attribute__((ext_vector_type(4))) unsigned;

DEV unsigned short f2bf(float f) {
  unsigned u = __builtin_bit_cast(unsigned, f);
  u = (u + 0x7fffu + ((u >> 16) & 1u)) >> 16;  // RNE
  return (unsigned short)u;
}

typedef __attribute__((address_space(1))) unsigned int as1_uint;
typedef __attribute__((address_space(3))) unsigned int as3_uint;

// async global->LDS, 16B per lane. LDS dest must be uniform base + lane*16.
DEV void gload_lds16(const void* g, void* l) {
  __builtin_amdgcn_global_load_lds(
      (as1_uint*)(uintptr_t)g,
      (as3_uint*)(unsigned int)(uintptr_t)l,
      16, 0, 0);
}

// fused fp32->bf16 convert for x | W_qkv | W_out (one launch).
#define N4_X  (4096 * 1024 / 4)
#define N4_WQ (3072 * 1024 / 4)
#define N4_WO (1024 * 1024 / 4)
__global__ __launch_bounds__(256) void cvt_all_k(const float* __restrict__ x,
                                                 const float* __restrict__ wq,
                                                 const float* __restrict__ wo,
                                                 unsigned short* __restrict__ xb,
                                                 unsigned short* __restrict__ wqb,
                                                 unsigned short* __restrict__ wob) {
  int i = blockIdx.x * 256 + threadIdx.x;
  const float* in; unsigned short* out;
  if (i < N4_X)                { in = x;  out = xb; }
  else if (i < N4_X + N4_WQ)   { i -= N4_X;  in = wq; out = wqb; }
  else                         { i -= N4_X + N4_WQ; in = wo; out = wob; }
  float4 v = reinterpret_cast<const float4*>(in)[i];
  ushort4 o;
  o.x = f2bf(v.x); o.y = f2bf(v.y); o.z = f2bf(v.z); o.w = f2bf(v.w);
  reinterpret_cast<ushort4*>(out)[i] = o;
}

// V [bh, s, d] -> V^T [bh, d, s].  64x64 tiles through swizzled LDS,
// coalesced global reads AND writes.
__global__ __launch_bounds__(256) void transpose_v_k(const unsigned short* __restrict__ V,
                                                     unsigned short* __restrict__ Vt) {
  const int bh = blockIdx.x;   // 32
  const int st = blockIdx.y;   // 32 s-tiles of 64
  const int tid = threadIdx.x;
  __shared__ unsigned short T[64 * 64];  // 8 KB
  const unsigned short* src = V + ((size_t)bh * 2048 + st * 64) * 64;  // contiguous 8KB

#pragma unroll
  for (int it = 0; it < 2; ++it) {
    const int c = it * 256 + tid;
    const int L = c * 16;
    const int S = L ^ (((L >> 10) & 7) << 4);
    gload_lds16((const char*)src + S, (char*)T + L);
  }
  __syncthreads();

#pragma unroll
  for (int it = 0; it < 2; ++it) {
    const int c = it * 256 + tid;
    const int d = c >> 3;
    const int s_off = (c & 7) * 8;
    const int xg = (c & 7) << 4;
    bf16x8 pk;
#pragma unroll
    for (int j = 0; j < 8; ++j)
      pk[j] = *(const short*)((const char*)T + (((s_off + j) * 128 + d * 2) ^ xg));
    *(bf16x8*)(Vt + (size_t)(bh * 64 + d) * VT_STRIDE + st * 64 + s_off) = pk;
  }
}

// C[M,N] = A[M,K](bf16) * W[N,K](bf16)^T + bias.
// MODE 0: Cout fp32 [M,N].  MODE 1: scatter to Q/K/V, all [bh, s, d] bf16 (coalesced).
// 128x128 tile, BK=64, 4 waves (2x2), 16x16x32 bf16 MFMA.
// 2-PHASE PIPELINE: double-buffered LDS staged via global_load_lds; per K-step
// {STAGE(next) -> s_waitcnt vmcnt(8) -> s_barrier -> MFMA -> s_barrier}.
// T2 XOR-swizzle via pre-swizzled global source.
template <int MODE, int N, int K>
__global__ __launch_bounds__(256) void gemm_bt(const unsigned short* __restrict__ A,
                                               const unsigned short* __restrict__ W,
                                               const float* __restrict__ bias,
                                               float* __restrict__ Cout,
                                               unsigned short* __restrict__ Qp,
                                               unsigned short* __restrict__ Kp,
                                               unsigned short* __restrict__ Vp) {
  __shared__ unsigned short As[2][128 * 64];
  __shared__ unsigned short Bs[2][128 * 64];
  const int tid = threadIdx.x;
  const int m0 = blockIdx.x * 128;
  const int n0 = blockIdx.y * 128;
  const int w = tid >> 6, lane = tid & 63, g = lane >> 4, lr = lane & 15;
  const int wr = w >> 1, wc = w & 1;
  const int xr = (lr & 7) << 4;

  f32x4 acc[4][4];
#pragma unroll
  for (int i = 0; i < 4; ++i)
#pragma unroll
    for (int j = 0; j < 4; ++j)
#pragma unroll
      for (int r = 0; r < 4; ++r) acc[i][j][r] = 0.f;

#define GSTAGE(buf, kt)                                                                     \
  do {                                                                                      \
    _Pragma("unroll")                                                                       \
    for (int it = 0; it < 4; ++it) {                                                        \
      const int c = it * 256 + tid;                                                         \
      const int row = c >> 3;                                                               \
      const int colb = ((c & 7) * 16) ^ ((row & 7) << 4);                                   \
      gload_lds16((const char*)(A + (size_t)(m0 + row) * K + (kt)) + colb,                  \
                  (char*)As[buf] + c * 16);                                                 \
      gload_lds16((const char*)(W + (size_t)(n0 + row) * K + (kt)) + colb,                  \
                  (char*)Bs[buf] + c * 16);                                                 \
    }                                                                                       \
  } while (0)

  GSTAGE(0, 0);
  int cur = 0;
  const int nsteps = K / 64;
  for (int step = 0; step < nsteps; ++step) {
    if (step + 1 < nsteps) {
      GSTAGE(cur ^ 1, (step + 1) * 64);
      asm volatile("s_waitcnt vmcnt(8)" ::: "memory");  // own tile loads landed; 8 newest in flight
    } else {
      asm volatile("s_waitcnt vmcnt(0)" ::: "memory");
    }
    __builtin_amdgcn_s_barrier();   // all waves' current-tile loads landed
    __builtin_amdgcn_sched_barrier(0);

    const char* AsC = (const char*)As[cur];
    const char* BsC = (const char*)Bs[cur];
    __builtin_amdgcn_s_setprio(1);
#pragma unroll
    for (int ks = 0; ks < 2; ++ks) {
      bf16x8 af[4], bf[4];
#pragma unroll
      for (int mi = 0; mi < 4; ++mi)
        af[mi] = *(const bf16x8*)(AsC +
                   ((((wr * 64 + mi * 16 + lr) * 128) + ks * 64 + g * 16) ^ xr));
#pragma unroll
      for (int ni = 0; ni < 4; ++ni)
        bf[ni] = *(const bf16x8*)(BsC +
                   ((((wc * 64 + ni * 16 + lr) * 128) + ks * 64 + g * 16) ^ xr));
#pragma unroll
      for (int mi = 0; mi < 4; ++mi)
#pragma unroll
        for (int ni = 0; ni < 4; ++ni)
          acc[mi][ni] = __builtin_amdgcn_mfma_f32_16x16x32_bf16(af[mi], bf[ni], acc[mi][ni], 0, 0, 0);
    }
    __builtin_amdgcn_s_setprio(0);

    asm volatile("" ::: "memory");
    __builtin_amdgcn_s_barrier();   // all waves done reading buf[cur]
    __builtin_amdgcn_sched_barrier(0);
    cur ^= 1;
  }
#undef GSTAGE

  if (MODE == 0) {
#pragma unroll
    for (int ni = 0; ni < 4; ++ni) {
      const int col = n0 + wc * 64 + ni * 16 + lr;
      const float bv = bias[col];
#pragma unroll
      for (int mi = 0; mi < 4; ++mi)
#pragma unroll
        for (int r = 0; r < 4; ++r) {
          const int row = m0 + wr * 64 + mi * 16 + g * 4 + r;
          Cout[(size_t)row * N + col] = acc[mi][ni][r] + bv;
        }
    }
  } else {
#pragma unroll
    for (int ni = 0; ni < 4; ++ni) {
      const int col = n0 + wc * 64 + ni * 16 + lr;
      const float bv = bias[col];
      const int which = col >> 10;
      const int h = (col >> 6) & 15;
      const int d = col & 63;
      unsigned short* P = which == 0 ? Qp : which == 1 ? Kp : Vp;
#pragma unroll
      for (int mi = 0; mi < 4; ++mi)
#pragma unroll
        for (int r = 0; r < 4; ++r) {
          const int row = m0 + wr * 64 + mi * 16 + g * 4 + r;
          const int b = row >> 11, s = row & 2047;
          P[(((size_t)(b * 16 + h) * 2048 + s) << 6) + d] = f2bf(acc[mi][ni][r] + bv);
        }
    }
  }
}

// Flash attention, causal. grid (bh=32, y=16), 256 threads = 4 waves.
// 32x32x16 MFMA; each wave owns 32 q-rows; block tile = 128 rows; ONE tile per
// block. Tile map: y<8 -> qt=15-y (heavy, dispatched first), y>=8 -> qt=y-8
// (light). 512 blocks = 2/CU = 8 waves/CU; round-robin placement pairs heavy+
// light on one CU at (32-2y)+(2y+2)=34 iters (uniform); otherwise LPT-ish.
// P never touches LDS: swapped QK^T leaves P[key][q=lane&31] in regs; cvt_pk +
// shfl_xor(32) cross-half exchange builds PV A-fragments in-register.
// K/V 64x64 tiles double-buffered (global_load_lds, pre-swizzled source),
// counted vmcnt(4). No-max exp2 softmax; per-lane l partial; 1 shfl reduce.
__global__ __launch_bounds__(256) void attn_fwd(const unsigned short* __restrict__ Q,
                                                const unsigned short* __restrict__ Kg,
                                                const unsigned short* __restrict__ Vt,
                                                unsigned short* __restrict__ AO) {
  const int bh = blockIdx.x;            // b*16 + h
  const int y  = blockIdx.y;            // 0..15
  const int qt = (y < 8) ? (15 - y) : (y - 8);
  const int tid = threadIdx.x;
  const int w = tid >> 6, lane = tid & 63;
  const int l31 = lane & 31, hi = lane >> 5;
  const int xr = (lane & 7) << 4;
  const unsigned short* Qp = Q  + (size_t)bh * 2048 * 64;
  const unsigned short* Kp = Kg + (size_t)bh * 2048 * 64;
  const unsigned short* Vp = Vt + (size_t)bh * 64 * VT_STRIDE;
  const int b = bh >> 4, h = bh & 15;

  __shared__ unsigned short Ks[2][64 * 64];  // 16 KB dbuf K
  __shared__ unsigned short Vs[2][64 * 64];  // 16 KB dbuf V^T

  const float C = 0.1803368801f;  // 0.125 * log2(e)

  const int L0 = tid * 16,         L1 = (tid + 256) * 16;
  const int G0 = L0 ^ (((L0 >> 7) & 7) << 4);
  const int G1 = L1 ^ (((L1 >> 7) & 7) << 4);

#define STAGE(buf, kvb)                                                                     \
  do {                                                                                      \
    gload_lds16((const char*)Kp + (size_t)(kvb) * 128 + G0, (char*)Ks[buf] + L0);           \
    gload_lds16((const char*)Kp + (size_t)(kvb) * 128 + G1, (char*)Ks[buf] + L1);           \
    gload_lds16((const char*)Vp + (size_t)(G0 >> 7) * (VT_STRIDE * 2) + (size_t)(kvb) * 2 + \
                    (G0 & 127), (char*)Vs[buf] + L0);                                       \
    gload_lds16((const char*)Vp + (size_t)(G1 >> 7) * (VT_STRIDE * 2) + (size_t)(kvb) * 2 + \
                    (G1 & 127), (char*)Vs[buf] + L1);                                       \
  } while (0)

  const int nb = 2 * qt + 2;             // kv blocks of 64 cover rows < 128*qt+128
  const int qrow0 = qt * 128 + w * 32;   // this wave's 32 q-rows

  STAGE(0, 0);
  int cur = 0;

  // Q as B-fragments: B[k=d][col=q=l31]; lane reads Q[qrow0+l31][ds*16+hi*8 .. +8]
  bf16x8 qf[4];
#pragma unroll
  for (int ds = 0; ds < 4; ++ds)
    qf[ds] = *(const bf16x8*)(Qp + (size_t)(qrow0 + l31) * 64 + ds * 16 + hi * 8);

  f32x16 o0, o1;       // O[q rows][d 0-31], [d 32-63]
#pragma unroll
  for (int r = 0; r < 16; ++r) { o0[r] = 0.f; o1[r] = 0.f; }
  float lp = 0.f;      // partial row-sum for q = l31 (keys this lane holds)

  for (int t = 0; t < nb; ++t) {
    const int kvb = t * 64;
    if (t + 1 < nb) {
      STAGE(cur ^ 1, (t + 1) * 64);
      asm volatile("s_waitcnt vmcnt(4)" ::: "memory");  // own tile-t loads landed
    } else {
      asm volatile("s_waitcnt vmcnt(0)" ::: "memory");
    }
    __builtin_amdgcn_s_barrier();        // all waves' tile-t loads landed
    __builtin_amdgcn_sched_barrier(0);

    const char* KsC = (const char*)Ks[cur];
    const char* VsC = (const char*)Vs[cur];

    // ---- QK^T SWAPPED (32x32x16): D[col=q=l31, row=key (reg,hi) layout] ----
    f32x16 s0, s1;     // key blocks 0-31, 32-63
#pragma unroll
    for (int r = 0; r < 16; ++r) { s0[r] = 0.f; s1[r] = 0.f; }
    __builtin_amdgcn_s_setprio(1);
#pragma unroll
    for (int ds = 0; ds < 4; ++ds) {
      bf16x8 k0 = *(const bf16x8*)(KsC + ((l31 * 128 + ds * 32 + hi * 16) ^ xr));
      bf16x8 k1 = *(const bf16x8*)(KsC + (((32 + l31) * 128 + ds * 32 + hi * 16) ^ xr));
      s0 = __builtin_amdgcn_mfma_f32_32x32x16_bf16(k0, qf[ds], s0, 0, 0, 0);
      s1 = __builtin_amdgcn_mfma_f32_32x32x16_bf16(k1, qf[ds], s1, 0, 0, 0);
    }
    __builtin_amdgcn_s_setprio(0);

    // ---- causal mask (last two kv blocks): key kvb+koff > q qrow0+l31 ----
    if (t >= nb - 2) {
      const int thr = qrow0 + l31 - kvb;
#pragma unroll
      for (int reg = 0; reg < 16; ++reg) {
        const int koff = (reg & 3) + 8 * (reg >> 2) + 4 * hi;
        if (koff > thr)      s0[reg] = -INFINITY;
        if (koff + 32 > thr) s1[reg] = -INFINITY;
      }
    }

    // ---- no-max softmax: p = exp2(s*C); per-lane partial sum ----
#pragma unroll
    for (int reg = 0; reg < 16; ++reg) {
      float a0 = exp2f(s0[reg] * C);
      float a1 = exp2f(s1[reg] * C);
      s0[reg] = a0; s1[reg] = a1;
      lp += a0 + a1;
    }

    // ---- pack P into PV A-frags (in-register; T12 shfl variant) ----
    bf16x8 pa[4];
#pragma unroll
    for (int kb = 0; kb < 2; ++kb) {
      unsigned wv[8], tv[8];
#pragma unroll
      for (int j = 0; j < 8; ++j) {
        float e0 = kb ? s1[2 * j] : s0[2 * j];
        float e1 = kb ? s1[2 * j + 1] : s0[2 * j + 1];
        asm("v_cvt_pk_bf16_f32 %0, %1, %2" : "=v"(wv[j]) : "v"(e0), "v"(e1));
      }
#pragma unroll
      for (int j = 0; j < 8; ++j) tv[j] = (unsigned)__shfl_xor((int)wv[j], 32);
      u32x4 ua, ub;
      ua[0] = hi ? tv[2] : wv[0]; ua[1] = hi ? tv[3] : wv[1];
      ua[2] = hi ? wv[2] : tv[0]; ua[3] = hi ? wv[3] : tv[1];
      ub[0] = hi ? tv[6] : wv[4]; ub[1] = hi ? tv[7] : wv[5];
      ub[2] = hi ? wv[6] : tv[4]; ub[3] = hi ? wv[7] : tv[5];
      pa[kb * 2]     = __builtin_bit_cast(bf16x8, ua);
      pa[kb * 2 + 1] = __builtin_bit_cast(bf16x8, ub);
    }

    // ---- PV (32x32x16): O[q][d] += P[q][k] V[k][d] ----
    __builtin_amdgcn_s_setprio(1);
#pragma unroll
    for (int ks = 0; ks < 4; ++ks) {
      bf16x8 v0 = *(const bf16x8*)(VsC + ((l31 * 128 + ks * 32 + hi * 16) ^ xr));
      bf16x8 v1 = *(const bf16x8*)(VsC + (((32 + l31) * 128 + ks * 32 + hi * 16) ^ xr));
      o0 = __builtin_amdgcn_mfma_f32_32x32x16_bf16(pa[ks], v0, o0, 0, 0, 0);
      o1 = __builtin_amdgcn_mfma_f32_32x32x16_bf16(pa[ks], v1, o1, 0, 0, 0);
    }
    __builtin_amdgcn_s_setprio(0);

    asm volatile("" ::: "memory");
    __builtin_amdgcn_s_barrier();        // all waves done reading buf[cur]
    __builtin_amdgcn_sched_barrier(0);
    cur ^= 1;
  }

  // ---- finalize: l lives split across lanes l31 / l31+32; one xor-reduce ----
  lp += __shfl_xor(lp, 32);
  const float inv = 1.0f / lp;           // valid for q = l31 on every lane
#pragma unroll
  for (int reg = 0; reg < 16; ++reg) {
    const int qoff = (reg & 3) + 8 * (reg >> 2) + 4 * hi;
    const float li = __shfl(inv, qoff);  // inv for q-row qoff (lane qoff holds it)
    const int row = qrow0 + qoff;
    AO[(size_t)(b * 2048 + row) * 1024 + h * 64 + l31]      = f2bf(o0[reg] * li);
    AO[(size_t)(b * 2048 + row) * 1024 + h * 64 + 32 + l31] = f2bf(o1[reg] * li);
  }
}

extern "C" void kernel_launch(void* const* d_in, const int* in_sizes, int n_in,
                              void* d_out, int out_size, void* d_ws, size_t ws_size,
                              hipStream_t stream) {
  const float* x     = (const float*)d_in[0];
  const float* W_qkv = (const float*)d_in[1];
  const float* b_qkv = (const float*)d_in[2];
  const float* W_out = (const float*)d_in[3];
  const float* b_out = (const float*)d_in[4];
  float* out = (float*)d_out;

  // workspace layout (48 MB exactly, fully rewritten every call)
  // AOb reuses xb's region: xb dead after QKV GEMM completes (stream-ordered).
  char* ws = (char*)d_ws;
  unsigned short* xb  = (unsigned short*)(ws);                      // 8 MB x bf16 [4096,1024]
  unsigned short* AOb = (unsigned short*)(ws);                      // 8 MB attn out (reuse)
  unsigned short* wqb = (unsigned short*)(ws + ((size_t)8 << 20));  // 6 MB W_qkv bf16
  unsigned short* wob = (unsigned short*)(ws + ((size_t)14 << 20)); // 2 MB W_out bf16
  unsigned short* Qb  = (unsigned short*)(ws + ((size_t)16 << 20)); // 8 MB Q [bh,s,d]
  unsigned short* Kb  = (unsigned short*)(ws + ((size_t)24 << 20)); // 8 MB K [bh,s,d]
  unsigned short* Vb  = (unsigned short*)(ws + ((size_t)32 << 20)); // 8 MB V [bh,s,d]
  unsigned short* Vtb = (unsigned short*)(ws + ((size_t)40 << 20)); // 8 MB V^T [bh,d,s]

  cvt_all_k<<<(N4_X + N4_WQ + N4_WO) / 256, 256, 0, stream>>>(x, W_qkv, W_out, xb, wqb, wob);

  gemm_bt<1, 3072, 1024><<<dim3(32, 24), 256, 0, stream>>>(xb, wqb, b_qkv, nullptr, Qb, Kb, Vb);
  transpose_v_k<<<dim3(32, 32), 256, 0, stream>>>(Vb, Vtb);
  attn_fwd<<<dim3(32, 16), 256, 0, stream>>>(Qb, Kb, Vtb, AOb);
  gemm_bt<0, 1024, 1024><<<dim3(32, 8), 256, 0, stream>>>(AOb, wob, b_out, out, nullptr, nullptr, nullptr);
}

// Round 15
// 116.431 us; speedup vs baseline: 1.0895x; 1.0620x over previous
//
#include <hip/hip_runtime.h>
#include <hip/hip_bf16.h>
#include <cstdint>

// MultiHeadAttention fused pipeline for MI355X (gfx950).
// Phases: cvt(fp32->bf16, fused) -> QKV GEMM (2-phase dbuf, bias + scatter Q/K/V;
//            Q pre-scaled by 0.125*log2e) -> V transpose -> flash attention
//            (causal, 32x32 MFMA, in-reg P, 2-wave blocks, dbuf LDS K/V)
//         -> out-proj GEMM (dbuf).

#define DEV __device__ __forceinline__

#define VT_STRIDE 2048  // V^T row stride in elems
#define QSCALE 0.1803368801f  // 0.125 * log2(e); folded into Q at QKV epilogue

using bf16x8 = __attribute__((ext_vector_type(8))) short;
using f32x4  = __attribute__((ext_vector_type(4))) float;
using f32x16 = __attribute__((ext_vector_type(16))) float;
using u32x4  = __attribute__((ext_vector_type(4))) unsigned;

DEV unsigned short f2bf(float f) {
  unsigned u = __builtin_bit_cast(unsigned, f);
  u = (u + 0x7fffu + ((u >> 16) & 1u)) >> 16;  // RNE
  return (unsigned short)u;
}

DEV float exp2_hw(float x) {  // exactly v_exp_f32: 2^x; exp2(-inf)=0
  float r;
  asm("v_exp_f32 %0, %1" : "=v"(r) : "v"(x));
  return r;
}

typedef __attribute__((address_space(1))) unsigned int as1_uint;
typedef __attribute__((address_space(3))) unsigned int as3_uint;

// async global->LDS, 16B per lane. LDS dest must be uniform base + lane*16.
DEV void gload_lds16(const void* g, void* l) {
  __builtin_amdgcn_global_load_lds(
      (as1_uint*)(uintptr_t)g,
      (as3_uint*)(unsigned int)(uintptr_t)l,
      16, 0, 0);
}

// fused fp32->bf16 convert for x | W_qkv | W_out (one launch).
#define N4_X  (4096 * 1024 / 4)
#define N4_WQ (3072 * 1024 / 4)
#define N4_WO (1024 * 1024 / 4)
__global__ __launch_bounds__(256) void cvt_all_k(const float* __restrict__ x,
                                                 const float* __restrict__ wq,
                                                 const float* __restrict__ wo,
                                                 unsigned short* __restrict__ xb,
                                                 unsigned short* __restrict__ wqb,
                                                 unsigned short* __restrict__ wob) {
  int i = blockIdx.x * 256 + threadIdx.x;
  const float* in; unsigned short* out;
  if (i < N4_X)                { in = x;  out = xb; }
  else if (i < N4_X + N4_WQ)   { i -= N4_X;  in = wq; out = wqb; }
  else                         { i -= N4_X + N4_WQ; in = wo; out = wob; }
  float4 v = reinterpret_cast<const float4*>(in)[i];
  ushort4 o;
  o.x = f2bf(v.x); o.y = f2bf(v.y); o.z = f2bf(v.z); o.w = f2bf(v.w);
  reinterpret_cast<ushort4*>(out)[i] = o;
}

// V [bh, s, d] -> V^T [bh, d, s].  64x64 tiles through swizzled LDS,
// coalesced global reads AND writes.
__global__ __launch_bounds__(256) void transpose_v_k(const unsigned short* __restrict__ V,
                                                     unsigned short* __restrict__ Vt) {
  const int bh = blockIdx.x;   // 32
  const int st = blockIdx.y;   // 32 s-tiles of 64
  const int tid = threadIdx.x;
  __shared__ unsigned short T[64 * 64];  // 8 KB
  const unsigned short* src = V + ((size_t)bh * 2048 + st * 64) * 64;  // contiguous 8KB

#pragma unroll
  for (int it = 0; it < 2; ++it) {
    const int c = it * 256 + tid;
    const int L = c * 16;
    const int S = L ^ (((L >> 10) & 7) << 4);
    gload_lds16((const char*)src + S, (char*)T + L);
  }
  __syncthreads();

#pragma unroll
  for (int it = 0; it < 2; ++it) {
    const int c = it * 256 + tid;
    const int d = c >> 3;
    const int s_off = (c & 7) * 8;
    const int xg = (c & 7) << 4;
    bf16x8 pk;
#pragma unroll
    for (int j = 0; j < 8; ++j)
      pk[j] = *(const short*)((const char*)T + (((s_off + j) * 128 + d * 2) ^ xg));
    *(bf16x8*)(Vt + (size_t)(bh * 64 + d) * VT_STRIDE + st * 64 + s_off) = pk;
  }
}

// C[M,N] = A[M,K](bf16) * W[N,K](bf16)^T + bias.
// MODE 0: Cout fp32 [M,N].  MODE 1: scatter to Q/K/V, all [bh, s, d] bf16 (coalesced);
//         Q additionally scaled by QSCALE so attn softmax is exp2(s) directly.
// 128x128 tile, BK=64, 4 waves (2x2), 16x16x32 bf16 MFMA.
// 2-PHASE PIPELINE: double-buffered LDS staged via global_load_lds; per K-step
// {STAGE(next) -> s_waitcnt vmcnt(8) -> s_barrier -> MFMA -> s_barrier}.
// T2 XOR-swizzle via pre-swizzled global source.
template <int MODE, int N, int K>
__global__ __launch_bounds__(256) void gemm_bt(const unsigned short* __restrict__ A,
                                               const unsigned short* __restrict__ W,
                                               const float* __restrict__ bias,
                                               float* __restrict__ Cout,
                                               unsigned short* __restrict__ Qp,
                                               unsigned short* __restrict__ Kp,
                                               unsigned short* __restrict__ Vp) {
  __shared__ unsigned short As[2][128 * 64];
  __shared__ unsigned short Bs[2][128 * 64];
  const int tid = threadIdx.x;
  const int m0 = blockIdx.x * 128;
  const int n0 = blockIdx.y * 128;
  const int w = tid >> 6, lane = tid & 63, g = lane >> 4, lr = lane & 15;
  const int wr = w >> 1, wc = w & 1;
  const int xr = (lr & 7) << 4;

  f32x4 acc[4][4];
#pragma unroll
  for (int i = 0; i < 4; ++i)
#pragma unroll
    for (int j = 0; j < 4; ++j)
#pragma unroll
      for (int r = 0; r < 4; ++r) acc[i][j][r] = 0.f;

#define GSTAGE(buf, kt)                                                                     \
  do {                                                                                      \
    _Pragma("unroll")                                                                       \
    for (int it = 0; it < 4; ++it) {                                                        \
      const int c = it * 256 + tid;                                                         \
      const int row = c >> 3;                                                               \
      const int colb = ((c & 7) * 16) ^ ((row & 7) << 4);                                   \
      gload_lds16((const char*)(A + (size_t)(m0 + row) * K + (kt)) + colb,                  \
                  (char*)As[buf] + c * 16);                                                 \
      gload_lds16((const char*)(W + (size_t)(n0 + row) * K + (kt)) + colb,                  \
                  (char*)Bs[buf] + c * 16);                                                 \
    }                                                                                       \
  } while (0)

  GSTAGE(0, 0);
  int cur = 0;
  const int nsteps = K / 64;
  for (int step = 0; step < nsteps; ++step) {
    if (step + 1 < nsteps) {
      GSTAGE(cur ^ 1, (step + 1) * 64);
      asm volatile("s_waitcnt vmcnt(8)" ::: "memory");  // own tile loads landed; 8 newest in flight
    } else {
      asm volatile("s_waitcnt vmcnt(0)" ::: "memory");
    }
    __builtin_amdgcn_s_barrier();   // all waves' current-tile loads landed
    __builtin_amdgcn_sched_barrier(0);

    const char* AsC = (const char*)As[cur];
    const char* BsC = (const char*)Bs[cur];
    __builtin_amdgcn_s_setprio(1);
#pragma unroll
    for (int ks = 0; ks < 2; ++ks) {
      bf16x8 af[4], bf[4];
#pragma unroll
      for (int mi = 0; mi < 4; ++mi)
        af[mi] = *(const bf16x8*)(AsC +
                   ((((wr * 64 + mi * 16 + lr) * 128) + ks * 64 + g * 16) ^ xr));
#pragma unroll
      for (int ni = 0; ni < 4; ++ni)
        bf[ni] = *(const bf16x8*)(BsC +
                   ((((wc * 64 + ni * 16 + lr) * 128) + ks * 64 + g * 16) ^ xr));
#pragma unroll
      for (int mi = 0; mi < 4; ++mi)
#pragma unroll
        for (int ni = 0; ni < 4; ++ni)
          acc[mi][ni] = __builtin_amdgcn_mfma_f32_16x16x32_bf16(af[mi], bf[ni], acc[mi][ni], 0, 0, 0);
    }
    __builtin_amdgcn_s_setprio(0);

    asm volatile("" ::: "memory");
    __builtin_amdgcn_s_barrier();   // all waves done reading buf[cur]
    __builtin_amdgcn_sched_barrier(0);
    cur ^= 1;
  }
#undef GSTAGE

  if (MODE == 0) {
#pragma unroll
    for (int ni = 0; ni < 4; ++ni) {
      const int col = n0 + wc * 64 + ni * 16 + lr;
      const float bv = bias[col];
#pragma unroll
      for (int mi = 0; mi < 4; ++mi)
#pragma unroll
        for (int r = 0; r < 4; ++r) {
          const int row = m0 + wr * 64 + mi * 16 + g * 4 + r;
          Cout[(size_t)row * N + col] = acc[mi][ni][r] + bv;
        }
    }
  } else {
#pragma unroll
    for (int ni = 0; ni < 4; ++ni) {
      const int col = n0 + wc * 64 + ni * 16 + lr;
      const float bv = bias[col];
      const int which = col >> 10;
      const int h = (col >> 6) & 15;
      const int d = col & 63;
      unsigned short* P = which == 0 ? Qp : which == 1 ? Kp : Vp;
      const float scl = which == 0 ? QSCALE : 1.0f;  // fold softmax scale into Q
#pragma unroll
      for (int mi = 0; mi < 4; ++mi)
#pragma unroll
        for (int r = 0; r < 4; ++r) {
          const int row = m0 + wr * 64 + mi * 16 + g * 4 + r;
          const int b = row >> 11, s = row & 2047;
          P[(((size_t)(b * 16 + h) * 2048 + s) << 6) + d] = f2bf((acc[mi][ni][r] + bv) * scl);
        }
    }
  }
}

// Flash attention, causal. grid (bh=32, y=32), 128 threads = 2 waves.
// qt = 31-y (heavy tiles dispatch first, LPT). Each wave owns 32 q-rows; block
// tile = 64 rows; 1024 blocks = 4 independent blocks/CU = 8 waves/CU (streams
// come from uncoupled blocks, not barrier-locked quads). 32x32x16 MFMA.
// P never touches LDS: swapped QK^T leaves P[key][q=lane&31] in regs; cvt_pk +
// shfl_xor(32) cross-half exchange builds PV A-fragments in-register.
// K/V 64x64 tiles double-buffered in swizzled LDS via global_load_lds
// (pre-swizzled source), counted vmcnt(8). Q pre-scaled -> p = v_exp(s) direct.
// Tile aligns with kv block -> mask only on the LAST kv block.
__global__ __launch_bounds__(128) void attn_fwd(const unsigned short* __restrict__ Q,
                                                const unsigned short* __restrict__ Kg,
                                                const unsigned short* __restrict__ Vt,
                                                unsigned short* __restrict__ AO) {
  const int bh = blockIdx.x;            // b*16 + h
  const int qt = 31 - blockIdx.y;       // 64-row q tile, heaviest first
  const int tid = threadIdx.x;
  const int w = tid >> 6, lane = tid & 63;
  const int l31 = lane & 31, hi = lane >> 5;
  const int xr = (lane & 7) << 4;
  const unsigned short* Qp = Q  + (size_t)bh * 2048 * 64;
  const unsigned short* Kp = Kg + (size_t)bh * 2048 * 64;
  const unsigned short* Vp = Vt + (size_t)bh * 64 * VT_STRIDE;
  const int b = bh >> 4, h = bh & 15;

  __shared__ unsigned short Ks[2][64 * 64];  // 16 KB dbuf K
  __shared__ unsigned short Vs[2][64 * 64];  // 16 KB dbuf V^T

  // staging: 128 threads x 4 chunks x 16B cover one 8KB tile (K and V each)
#define STAGE(buf, kvb)                                                                     \
  do {                                                                                      \
    _Pragma("unroll")                                                                       \
    for (int it = 0; it < 4; ++it) {                                                        \
      const int Lc = (it * 128 + tid) * 16;                                                 \
      const int Gc = Lc ^ (((Lc >> 7) & 7) << 4);                                           \
      gload_lds16((const char*)Kp + (size_t)(kvb) * 128 + Gc, (char*)Ks[buf] + Lc);         \
      gload_lds16((const char*)Vp + (size_t)(Gc >> 7) * (VT_STRIDE * 2) +                   \
                      (size_t)(kvb) * 2 + (Gc & 127), (char*)Vs[buf] + Lc);                 \
    }                                                                                       \
  } while (0)

  const int nb = qt + 1;                 // kv blocks of 64 cover rows < 64*qt+64
  const int qrow0 = qt * 64 + w * 32;    // this wave's 32 q-rows

  STAGE(0, 0);
  int cur = 0;

  // Q as B-fragments: B[k=d][col=q=l31]; lane reads Q[qrow0+l31][ds*16+hi*8 .. +8]
  bf16x8 qf[4];
#pragma unroll
  for (int ds = 0; ds < 4; ++ds)
    qf[ds] = *(const bf16x8*)(Qp + (size_t)(qrow0 + l31) * 64 + ds * 16 + hi * 8);

  f32x16 o0, o1;       // O[q rows][d 0-31], [d 32-63]
#pragma unroll
  for (int r = 0; r < 16; ++r) { o0[r] = 0.f; o1[r] = 0.f; }
  float lp = 0.f;      // partial row-sum for q = l31 (keys this lane holds)

  for (int t = 0; t < nb; ++t) {
    const int kvb = t * 64;
    if (t + 1 < nb) {
      STAGE(cur ^ 1, (t + 1) * 64);
      asm volatile("s_waitcnt vmcnt(8)" ::: "memory");  // own tile-t loads landed
    } else {
      asm volatile("s_waitcnt vmcnt(0)" ::: "memory");
    }
    __builtin_amdgcn_s_barrier();        // both waves' tile-t loads landed
    __builtin_amdgcn_sched_barrier(0);

    const char* KsC = (const char*)Ks[cur];
    const char* VsC = (const char*)Vs[cur];

    // ---- QK^T SWAPPED (32x32x16): D[col=q=l31, row=key (reg,hi) layout] ----
    f32x16 s0, s1;     // key blocks 0-31, 32-63
#pragma unroll
    for (int r = 0; r < 16; ++r) { s0[r] = 0.f; s1[r] = 0.f; }
    __builtin_amdgcn_s_setprio(1);
#pragma unroll
    for (int ds = 0; ds < 4; ++ds) {
      bf16x8 k0 = *(const bf16x8*)(KsC + ((l31 * 128 + ds * 32 + hi * 16) ^ xr));
      bf16x8 k1 = *(const bf16x8*)(KsC + (((32 + l31) * 128 + ds * 32 + hi * 16) ^ xr));
      s0 = __builtin_amdgcn_mfma_f32_32x32x16_bf16(k0, qf[ds], s0, 0, 0, 0);
      s1 = __builtin_amdgcn_mfma_f32_32x32x16_bf16(k1, qf[ds], s1, 0, 0, 0);
    }
    __builtin_amdgcn_s_setprio(0);

    // ---- causal mask (last kv block only; tile == diagonal block) ----
    if (t == nb - 1) {
      const int thr = w * 32 + l31;      // q row within tile == key threshold
#pragma unroll
      for (int reg = 0; reg < 16; ++reg) {
        const int koff = (reg & 3) + 8 * (reg >> 2) + 4 * hi;
        if (koff > thr)      s0[reg] = -INFINITY;
        if (koff + 32 > thr) s1[reg] = -INFINITY;
      }
    }

    // ---- softmax: p = v_exp(s) (Q pre-scaled); per-lane partial sum ----
#pragma unroll
    for (int reg = 0; reg < 16; ++reg) {
      float a0 = exp2_hw(s0[reg]);
      float a1 = exp2_hw(s1[reg]);
      s0[reg] = a0; s1[reg] = a1;
      lp += a0 + a1;
    }

    // ---- pack P into PV A-frags (in-register; cvt_pk + shfl_xor(32)) ----
    bf16x8 pa[4];
#pragma unroll
    for (int kb = 0; kb < 2; ++kb) {
      unsigned wv[8], tv[8];
#pragma unroll
      for (int j = 0; j < 8; ++j) {
        float e0 = kb ? s1[2 * j] : s0[2 * j];
        float e1 = kb ? s1[2 * j + 1] : s0[2 * j + 1];
        asm("v_cvt_pk_bf16_f32 %0, %1, %2" : "=v"(wv[j]) : "v"(e0), "v"(e1));
      }
#pragma unroll
      for (int j = 0; j < 8; ++j) tv[j] = (unsigned)__shfl_xor((int)wv[j], 32);
      u32x4 ua, ub;
      ua[0] = hi ? tv[2] : wv[0]; ua[1] = hi ? tv[3] : wv[1];
      ua[2] = hi ? wv[2] : tv[0]; ua[3] = hi ? wv[3] : tv[1];
      ub[0] = hi ? tv[6] : wv[4]; ub[1] = hi ? tv[7] : wv[5];
      ub[2] = hi ? wv[6] : tv[4]; ub[3] = hi ? wv[7] : tv[5];
      pa[kb * 2]     = __builtin_bit_cast(bf16x8, ua);
      pa[kb * 2 + 1] = __builtin_bit_cast(bf16x8, ub);
    }

    // ---- PV (32x32x16): O[q][d] += P[q][k] V[k][d] ----
    __builtin_amdgcn_s_setprio(1);
#pragma unroll
    for (int ks = 0; ks < 4; ++ks) {
      bf16x8 v0 = *(const bf16x8*)(VsC + ((l31 * 128 + ks * 32 + hi * 16) ^ xr));
      bf16x8 v1 = *(const bf16x8*)(VsC + (((32 + l31) * 128 + ks * 32 + hi * 16) ^ xr));
      o0 = __builtin_amdgcn_mfma_f32_32x32x16_bf16(pa[ks], v0, o0, 0, 0, 0);
      o1 = __builtin_amdgcn_mfma_f32_32x32x16_bf16(pa[ks], v1, o1, 0, 0, 0);
    }
    __builtin_amdgcn_s_setprio(0);

    asm volatile("" ::: "memory");
    __builtin_amdgcn_s_barrier();        // both waves done reading buf[cur]
    __builtin_amdgcn_sched_barrier(0);
    cur ^= 1;
  }

  // ---- finalize: l lives split across lanes l31 / l31+32; one xor-reduce ----
  lp += __shfl_xor(lp, 32);
  const float inv = 1.0f / lp;           // valid for q = l31 on every lane
#pragma unroll
  for (int reg = 0; reg < 16; ++reg) {
    const int qoff = (reg & 3) + 8 * (reg >> 2) + 4 * hi;
    const float li = __shfl(inv, qoff);  // inv for q-row qoff (lane qoff holds it)
    const int row = qrow0 + qoff;
    AO[(size_t)(b * 2048 + row) * 1024 + h * 64 + l31]      = f2bf(o0[reg] * li);
    AO[(size_t)(b * 2048 + row) * 1024 + h * 64 + 32 + l31] = f2bf(o1[reg] * li);
  }
#undef STAGE
}

extern "C" void kernel_launch(void* const* d_in, const int* in_sizes, int n_in,
                              void* d_out, int out_size, void* d_ws, size_t ws_size,
                              hipStream_t stream) {
  const float* x     = (const float*)d_in[0];
  const float* W_qkv = (const float*)d_in[1];
  const float* b_qkv = (const float*)d_in[2];
  const float* W_out = (const float*)d_in[3];
  const float* b_out = (const float*)d_in[4];
  float* out = (float*)d_out;

  // workspace layout (48 MB exactly, fully rewritten every call)
  // AOb reuses xb's region: xb dead after QKV GEMM completes (stream-ordered).
  char* ws = (char*)d_ws;
  unsigned short* xb  = (unsigned short*)(ws);                      // 8 MB x bf16 [4096,1024]
  unsigned short* AOb = (unsigned short*)(ws);                      // 8 MB attn out (reuse)
  unsigned short* wqb = (unsigned short*)(ws + ((size_t)8 << 20));  // 6 MB W_qkv bf16
  unsigned short* wob = (unsigned short*)(ws + ((size_t)14 << 20)); // 2 MB W_out bf16
  unsigned short* Qb  = (unsigned short*)(ws + ((size_t)16 << 20)); // 8 MB Q [bh,s,d] (pre-scaled)
  unsigned short* Kb  = (unsigned short*)(ws + ((size_t)24 << 20)); // 8 MB K [bh,s,d]
  unsigned short* Vb  = (unsigned short*)(ws + ((size_t)32 << 20)); // 8 MB V [bh,s,d]
  unsigned short* Vtb = (unsigned short*)(ws + ((size_t)40 << 20)); // 8 MB V^T [bh,d,s]

  cvt_all_k<<<(N4_X + N4_WQ + N4_WO) / 256, 256, 0, stream>>>(x, W_qkv, W_out, xb, wqb, wob);

  gemm_bt<1, 3072, 1024><<<dim3(32, 24), 256, 0, stream>>>(xb, wqb, b_qkv, nullptr, Qb, Kb, Vb);
  transpose_v_k<<<dim3(32, 32), 256, 0, stream>>>(Vb, Vtb);
  attn_fwd<<<dim3(32, 32), 128, 0, stream>>>(Qb, Kb, Vtb, AOb);
  gemm_bt<0, 1024, 1024><<<dim3(32, 8), 256, 0, stream>>>(AOb, wob, b_out, out, nullptr, nullptr, nullptr);
}

// Round 16
// 115.897 us; speedup vs baseline: 1.0945x; 1.0046x over previous
//
#include <hip/hip_runtime.h>
#include <hip/hip_bf16.h>
#include <cstdint>

// MultiHeadAttention fused pipeline for MI355X (gfx950).
// Phases: cvt(fp32->bf16, fused) -> QKV GEMM (2-phase dbuf, bias + scatter Q/K/V;
//            Q pre-scaled by 0.125*log2e) -> V transpose -> flash attention
//            (causal, 32x32 MFMA, in-reg P, PV deferred one iteration so
//            PV(t-1) || QK(t) fill the MFMA pipe) -> out-proj GEMM (dbuf).

#define DEV __device__ __forceinline__

#define VT_STRIDE 2048  // V^T row stride in elems
#define QSCALE 0.1803368801f  // 0.125 * log2(e); folded into Q at QKV epilogue

using bf16x8 = __attribute__((ext_vector_type(8))) short;
using f32x4  = __attribute__((ext_vector_type(4))) float;
using f32x16 = __attribute__((ext_vector_type(16))) float;
using u32x4  = __attribute__((ext_vector_type(4))) unsigned;

DEV unsigned short f2bf(float f) {
  unsigned u = __builtin_bit_cast(unsigned, f);
  u = (u + 0x7fffu + ((u >> 16) & 1u)) >> 16;  // RNE
  return (unsigned short)u;
}

DEV float exp2_hw(float x) {  // exactly v_exp_f32: 2^x; exp2(-inf)=0
  float r;
  asm("v_exp_f32 %0, %1" : "=v"(r) : "v"(x));
  return r;
}

typedef __attribute__((address_space(1))) unsigned int as1_uint;
typedef __attribute__((address_space(3))) unsigned int as3_uint;

// async global->LDS, 16B per lane. LDS dest must be uniform base + lane*16.
DEV void gload_lds16(const void* g, void* l) {
  __builtin_amdgcn_global_load_lds(
      (as1_uint*)(uintptr_t)g,
      (as3_uint*)(unsigned int)(uintptr_t)l,
      16, 0, 0);
}

// fused fp32->bf16 convert for x | W_qkv | W_out (one launch).
#define N4_X  (4096 * 1024 / 4)
#define N4_WQ (3072 * 1024 / 4)
#define N4_WO (1024 * 1024 / 4)
__global__ __launch_bounds__(256) void cvt_all_k(const float* __restrict__ x,
                                                 const float* __restrict__ wq,
                                                 const float* __restrict__ wo,
                                                 unsigned short* __restrict__ xb,
                                                 unsigned short* __restrict__ wqb,
                                                 unsigned short* __restrict__ wob) {
  int i = blockIdx.x * 256 + threadIdx.x;
  const float* in; unsigned short* out;
  if (i < N4_X)                { in = x;  out = xb; }
  else if (i < N4_X + N4_WQ)   { i -= N4_X;  in = wq; out = wqb; }
  else                         { i -= N4_X + N4_WQ; in = wo; out = wob; }
  float4 v = reinterpret_cast<const float4*>(in)[i];
  ushort4 o;
  o.x = f2bf(v.x); o.y = f2bf(v.y); o.z = f2bf(v.z); o.w = f2bf(v.w);
  reinterpret_cast<ushort4*>(out)[i] = o;
}

// V [bh, s, d] -> V^T [bh, d, s].  64x64 tiles through swizzled LDS,
// coalesced global reads AND writes.
__global__ __launch_bounds__(256) void transpose_v_k(const unsigned short* __restrict__ V,
                                                     unsigned short* __restrict__ Vt) {
  const int bh = blockIdx.x;   // 32
  const int st = blockIdx.y;   // 32 s-tiles of 64
  const int tid = threadIdx.x;
  __shared__ unsigned short T[64 * 64];  // 8 KB
  const unsigned short* src = V + ((size_t)bh * 2048 + st * 64) * 64;  // contiguous 8KB

#pragma unroll
  for (int it = 0; it < 2; ++it) {
    const int c = it * 256 + tid;
    const int L = c * 16;
    const int S = L ^ (((L >> 10) & 7) << 4);
    gload_lds16((const char*)src + S, (char*)T + L);
  }
  __syncthreads();

#pragma unroll
  for (int it = 0; it < 2; ++it) {
    const int c = it * 256 + tid;
    const int d = c >> 3;
    const int s_off = (c & 7) * 8;
    const int xg = (c & 7) << 4;
    bf16x8 pk;
#pragma unroll
    for (int j = 0; j < 8; ++j)
      pk[j] = *(const short*)((const char*)T + (((s_off + j) * 128 + d * 2) ^ xg));
    *(bf16x8*)(Vt + (size_t)(bh * 64 + d) * VT_STRIDE + st * 64 + s_off) = pk;
  }
}

// C[M,N] = A[M,K](bf16) * W[N,K](bf16)^T + bias.
// MODE 0: Cout fp32 [M,N].  MODE 1: scatter to Q/K/V, all [bh, s, d] bf16 (coalesced);
//         Q additionally scaled by QSCALE so attn softmax is exp2(s) directly.
// 128x128 tile, BK=64, 4 waves (2x2), 16x16x32 bf16 MFMA.
// 2-PHASE PIPELINE: double-buffered LDS staged via global_load_lds; per K-step
// {STAGE(next) -> s_waitcnt vmcnt(8) -> s_barrier -> MFMA -> s_barrier}.
// T2 XOR-swizzle via pre-swizzled global source.
template <int MODE, int N, int K>
__global__ __launch_bounds__(256) void gemm_bt(const unsigned short* __restrict__ A,
                                               const unsigned short* __restrict__ W,
                                               const float* __restrict__ bias,
                                               float* __restrict__ Cout,
                                               unsigned short* __restrict__ Qp,
                                               unsigned short* __restrict__ Kp,
                                               unsigned short* __restrict__ Vp) {
  __shared__ unsigned short As[2][128 * 64];
  __shared__ unsigned short Bs[2][128 * 64];
  const int tid = threadIdx.x;
  const int m0 = blockIdx.x * 128;
  const int n0 = blockIdx.y * 128;
  const int w = tid >> 6, lane = tid & 63, g = lane >> 4, lr = lane & 15;
  const int wr = w >> 1, wc = w & 1;
  const int xr = (lr & 7) << 4;

  f32x4 acc[4][4];
#pragma unroll
  for (int i = 0; i < 4; ++i)
#pragma unroll
    for (int j = 0; j < 4; ++j)
#pragma unroll
      for (int r = 0; r < 4; ++r) acc[i][j][r] = 0.f;

#define GSTAGE(buf, kt)                                                                     \
  do {                                                                                      \
    _Pragma("unroll")                                                                       \
    for (int it = 0; it < 4; ++it) {                                                        \
      const int c = it * 256 + tid;                                                         \
      const int row = c >> 3;                                                               \
      const int colb = ((c & 7) * 16) ^ ((row & 7) << 4);                                   \
      gload_lds16((const char*)(A + (size_t)(m0 + row) * K + (kt)) + colb,                  \
                  (char*)As[buf] + c * 16);                                                 \
      gload_lds16((const char*)(W + (size_t)(n0 + row) * K + (kt)) + colb,                  \
                  (char*)Bs[buf] + c * 16);                                                 \
    }                                                                                       \
  } while (0)

  GSTAGE(0, 0);
  int cur = 0;
  const int nsteps = K / 64;
  for (int step = 0; step < nsteps; ++step) {
    if (step + 1 < nsteps) {
      GSTAGE(cur ^ 1, (step + 1) * 64);
      asm volatile("s_waitcnt vmcnt(8)" ::: "memory");  // own tile loads landed; 8 newest in flight
    } else {
      asm volatile("s_waitcnt vmcnt(0)" ::: "memory");
    }
    __builtin_amdgcn_s_barrier();   // all waves' current-tile loads landed
    __builtin_amdgcn_sched_barrier(0);

    const char* AsC = (const char*)As[cur];
    const char* BsC = (const char*)Bs[cur];
    __builtin_amdgcn_s_setprio(1);
#pragma unroll
    for (int ks = 0; ks < 2; ++ks) {
      bf16x8 af[4], bf[4];
#pragma unroll
      for (int mi = 0; mi < 4; ++mi)
        af[mi] = *(const bf16x8*)(AsC +
                   ((((wr * 64 + mi * 16 + lr) * 128) + ks * 64 + g * 16) ^ xr));
#pragma unroll
      for (int ni = 0; ni < 4; ++ni)
        bf[ni] = *(const bf16x8*)(BsC +
                   ((((wc * 64 + ni * 16 + lr) * 128) + ks * 64 + g * 16) ^ xr));
#pragma unroll
      for (int mi = 0; mi < 4; ++mi)
#pragma unroll
        for (int ni = 0; ni < 4; ++ni)
          acc[mi][ni] = __builtin_amdgcn_mfma_f32_16x16x32_bf16(af[mi], bf[ni], acc[mi][ni], 0, 0, 0);
    }
    __builtin_amdgcn_s_setprio(0);

    asm volatile("" ::: "memory");
    __builtin_amdgcn_s_barrier();   // all waves done reading buf[cur]
    __builtin_amdgcn_sched_barrier(0);
    cur ^= 1;
  }
#undef GSTAGE

  if (MODE == 0) {
#pragma unroll
    for (int ni = 0; ni < 4; ++ni) {
      const int col = n0 + wc * 64 + ni * 16 + lr;
      const float bv = bias[col];
#pragma unroll
      for (int mi = 0; mi < 4; ++mi)
#pragma unroll
        for (int r = 0; r < 4; ++r) {
          const int row = m0 + wr * 64 + mi * 16 + g * 4 + r;
          Cout[(size_t)row * N + col] = acc[mi][ni][r] + bv;
        }
    }
  } else {
#pragma unroll
    for (int ni = 0; ni < 4; ++ni) {
      const int col = n0 + wc * 64 + ni * 16 + lr;
      const float bv = bias[col];
      const int which = col >> 10;
      const int h = (col >> 6) & 15;
      const int d = col & 63;
      unsigned short* P = which == 0 ? Qp : which == 1 ? Kp : Vp;
      const float scl = which == 0 ? QSCALE : 1.0f;  // fold softmax scale into Q
#pragma unroll
      for (int mi = 0; mi < 4; ++mi)
#pragma unroll
        for (int r = 0; r < 4; ++r) {
          const int row = m0 + wr * 64 + mi * 16 + g * 4 + r;
          const int b = row >> 11, s = row & 2047;
          P[(((size_t)(b * 16 + h) * 2048 + s) << 6) + d] = f2bf((acc[mi][ni][r] + bv) * scl);
        }
    }
  }
}

// Flash attention, causal. grid (bh=32, y=32), 128 threads = 2 waves.
// Tile map qt = (y<16) ? 31-y : y-16: under round-robin placement each CU's
// 4 blocks sum to exactly 66 kv-iterations (uniform makespan). Each wave owns
// 32 q-rows; block tile = 64 rows; 1024 blocks = 4/CU = 8 waves/CU. 32x32x16.
// SOFTWARE PIPELINE: PV deferred one iteration. Body = {PV(t-1)[regs] || QK(t)}
// -> V(t)-frag ds_reads -> softmax+pack(t). The 16 MFMAs at iteration start
// have no in-iteration dependencies, filling the matrix pipe while K loads.
// lgkmcnt(0) before the end barrier protects reg-held V frags from the next
// STAGE overwrite. P never touches LDS (cvt_pk + shfl_xor(32) exchange).
// Q pre-scaled -> p = v_exp(s). Mask only on the last kv block.
__global__ __launch_bounds__(128) void attn_fwd(const unsigned short* __restrict__ Q,
                                                const unsigned short* __restrict__ Kg,
                                                const unsigned short* __restrict__ Vt,
                                                unsigned short* __restrict__ AO) {
  const int bh = blockIdx.x;            // b*16 + h
  const int y  = blockIdx.y;            // 0..31
  const int qt = (y < 16) ? (31 - y) : (y - 16);  // balanced LPT map
  const int tid = threadIdx.x;
  const int w = tid >> 6, lane = tid & 63;
  const int l31 = lane & 31, hi = lane >> 5;
  const int xr = (lane & 7) << 4;
  const unsigned short* Qp = Q  + (size_t)bh * 2048 * 64;
  const unsigned short* Kp = Kg + (size_t)bh * 2048 * 64;
  const unsigned short* Vp = Vt + (size_t)bh * 64 * VT_STRIDE;
  const int b = bh >> 4, h = bh & 15;

  __shared__ unsigned short Ks[2][64 * 64];  // 16 KB dbuf K
  __shared__ unsigned short Vs[2][64 * 64];  // 16 KB dbuf V^T

  // staging: 128 threads x 4 chunks x 16B cover one 8KB tile (K and V each)
#define STAGE(buf, kvb)                                                                     \
  do {                                                                                      \
    _Pragma("unroll")                                                                       \
    for (int it = 0; it < 4; ++it) {                                                        \
      const int Lc = (it * 128 + tid) * 16;                                                 \
      const int Gc = Lc ^ (((Lc >> 7) & 7) << 4);                                           \
      gload_lds16((const char*)Kp + (size_t)(kvb) * 128 + Gc, (char*)Ks[buf] + Lc);         \
      gload_lds16((const char*)Vp + (size_t)(Gc >> 7) * (VT_STRIDE * 2) +                   \
                      (size_t)(kvb) * 2 + (Gc & 127), (char*)Vs[buf] + Lc);                 \
    }                                                                                       \
  } while (0)

  const int nb = qt + 1;                 // kv blocks of 64 cover rows < 64*qt+64
  const int qrow0 = qt * 64 + w * 32;    // this wave's 32 q-rows

  STAGE(0, 0);
  int cur = 0;

  // Q as B-fragments: B[k=d][col=q=l31]
  bf16x8 qf[4];
#pragma unroll
  for (int ds = 0; ds < 4; ++ds)
    qf[ds] = *(const bf16x8*)(Qp + (size_t)(qrow0 + l31) * 64 + ds * 16 + hi * 8);

  f32x16 o0, o1;       // O[q rows][d 0-31], [d 32-63]
#pragma unroll
  for (int r = 0; r < 16; ++r) { o0[r] = 0.f; o1[r] = 0.f; }
  float lp = 0.f;      // partial row-sum for q = l31 (keys this lane holds)

  bf16x8 pa[4];        // P fragments of iteration t-1 (registers)
  bf16x8 vf[8];        // V fragments of iteration t-1 (registers)

  for (int t = 0; t < nb; ++t) {
    if (t + 1 < nb) {
      STAGE(cur ^ 1, (t + 1) * 64);
      asm volatile("s_waitcnt vmcnt(8)" ::: "memory");  // own tile-t loads landed
    } else {
      asm volatile("s_waitcnt vmcnt(0)" ::: "memory");
    }
    __builtin_amdgcn_s_barrier();        // both waves' tile-t loads landed
    __builtin_amdgcn_sched_barrier(0);

    const char* KsC = (const char*)Ks[cur];
    const char* VsC = (const char*)Vs[cur];

    // ---- MFMA phase: PV(t-1) [all-register] || QK(t) ----
    f32x16 s0, s1;     // scores, key blocks 0-31 / 32-63
#pragma unroll
    for (int r = 0; r < 16; ++r) { s0[r] = 0.f; s1[r] = 0.f; }
    __builtin_amdgcn_s_setprio(1);
    if (t > 0) {
#pragma unroll
      for (int ks = 0; ks < 4; ++ks) {
        o0 = __builtin_amdgcn_mfma_f32_32x32x16_bf16(pa[ks], vf[ks * 2],     o0, 0, 0, 0);
        o1 = __builtin_amdgcn_mfma_f32_32x32x16_bf16(pa[ks], vf[ks * 2 + 1], o1, 0, 0, 0);
      }
    }
#pragma unroll
    for (int ds = 0; ds < 4; ++ds) {
      bf16x8 k0 = *(const bf16x8*)(KsC + ((l31 * 128 + ds * 32 + hi * 16) ^ xr));
      bf16x8 k1 = *(const bf16x8*)(KsC + (((32 + l31) * 128 + ds * 32 + hi * 16) ^ xr));
      s0 = __builtin_amdgcn_mfma_f32_32x32x16_bf16(k0, qf[ds], s0, 0, 0, 0);
      s1 = __builtin_amdgcn_mfma_f32_32x32x16_bf16(k1, qf[ds], s1, 0, 0, 0);
    }
    __builtin_amdgcn_s_setprio(0);

    // ---- V(t) fragments -> registers (consumed by PV at t+1) ----
#pragma unroll
    for (int ks = 0; ks < 4; ++ks) {
      vf[ks * 2]     = *(const bf16x8*)(VsC + ((l31 * 128 + ks * 32 + hi * 16) ^ xr));
      vf[ks * 2 + 1] = *(const bf16x8*)(VsC + (((32 + l31) * 128 + ks * 32 + hi * 16) ^ xr));
    }

    // ---- causal mask (last kv block only; tile == diagonal block) ----
    if (t == nb - 1) {
      const int thr = w * 32 + l31;      // q row within tile == key threshold
#pragma unroll
      for (int reg = 0; reg < 16; ++reg) {
        const int koff = (reg & 3) + 8 * (reg >> 2) + 4 * hi;
        if (koff > thr)      s0[reg] = -INFINITY;
        if (koff + 32 > thr) s1[reg] = -INFINITY;
      }
    }

    // ---- softmax: p = v_exp(s); per-lane partial sum ----
#pragma unroll
    for (int reg = 0; reg < 16; ++reg) {
      float a0 = exp2_hw(s0[reg]);
      float a1 = exp2_hw(s1[reg]);
      s0[reg] = a0; s1[reg] = a1;
      lp += a0 + a1;
    }

    // ---- pack P into A-frags for next iteration's PV ----
#pragma unroll
    for (int kb = 0; kb < 2; ++kb) {
      unsigned wv[8], tv[8];
#pragma unroll
      for (int j = 0; j < 8; ++j) {
        float e0 = kb ? s1[2 * j] : s0[2 * j];
        float e1 = kb ? s1[2 * j + 1] : s0[2 * j + 1];
        asm("v_cvt_pk_bf16_f32 %0, %1, %2" : "=v"(wv[j]) : "v"(e0), "v"(e1));
      }
#pragma unroll
      for (int j = 0; j < 8; ++j) tv[j] = (unsigned)__shfl_xor((int)wv[j], 32);
      u32x4 ua, ub;
      ua[0] = hi ? tv[2] : wv[0]; ua[1] = hi ? tv[3] : wv[1];
      ua[2] = hi ? wv[2] : tv[0]; ua[3] = hi ? wv[3] : tv[1];
      ub[0] = hi ? tv[6] : wv[4]; ub[1] = hi ? tv[7] : wv[5];
      ub[2] = hi ? wv[6] : tv[4]; ub[3] = hi ? wv[7] : tv[5];
      pa[kb * 2]     = __builtin_bit_cast(bf16x8, ua);
      pa[kb * 2 + 1] = __builtin_bit_cast(bf16x8, ub);
    }

    // V-frag reads must complete before any wave's next STAGE overwrites Vs
    asm volatile("s_waitcnt lgkmcnt(0)" ::: "memory");
    __builtin_amdgcn_s_barrier();
    __builtin_amdgcn_sched_barrier(0);
    cur ^= 1;
  }

  // ---- epilogue PV for the final tile ----
#pragma unroll
  for (int ks = 0; ks < 4; ++ks) {
    o0 = __builtin_amdgcn_mfma_f32_32x32x16_bf16(pa[ks], vf[ks * 2],     o0, 0, 0, 0);
    o1 = __builtin_amdgcn_mfma_f32_32x32x16_bf16(pa[ks], vf[ks * 2 + 1], o1, 0, 0, 0);
  }

  // ---- finalize: l lives split across lanes l31 / l31+32; one xor-reduce ----
  lp += __shfl_xor(lp, 32);
  const float inv = 1.0f / lp;           // valid for q = l31 on every lane
#pragma unroll
  for (int reg = 0; reg < 16; ++reg) {
    const int qoff = (reg & 3) + 8 * (reg >> 2) + 4 * hi;
    const float li = __shfl(inv, qoff);  // inv for q-row qoff (lane qoff holds it)
    const int row = qrow0 + qoff;
    AO[(size_t)(b * 2048 + row) * 1024 + h * 64 + l31]      = f2bf(o0[reg] * li);
    AO[(size_t)(b * 2048 + row) * 1024 + h * 64 + 32 + l31] = f2bf(o1[reg] * li);
  }
#undef STAGE
}

extern "C" void kernel_launch(void* const* d_in, const int* in_sizes, int n_in,
                              void* d_out, int out_size, void* d_ws, size_t ws_size,
                              hipStream_t stream) {
  const float* x     = (const float*)d_in[0];
  const float* W_qkv = (const float*)d_in[1];
  const float* b_qkv = (const float*)d_in[2];
  const float* W_out = (const float*)d_in[3];
  const float* b_out = (const float*)d_in[4];
  float* out = (float*)d_out;

  // workspace layout (48 MB exactly, fully rewritten every call)
  // AOb reuses xb's region: xb dead after QKV GEMM completes (stream-ordered).
  char* ws = (char*)d_ws;
  unsigned short* xb  = (unsigned short*)(ws);                      // 8 MB x bf16 [4096,1024]
  unsigned short* AOb = (unsigned short*)(ws);                      // 8 MB attn out (reuse)
  unsigned short* wqb = (unsigned short*)(ws + ((size_t)8 << 20));  // 6 MB W_qkv bf16
  unsigned short* wob = (unsigned short*)(ws + ((size_t)14 << 20)); // 2 MB W_out bf16
  unsigned short* Qb  = (unsigned short*)(ws + ((size_t)16 << 20)); // 8 MB Q [bh,s,d] (pre-scaled)
  unsigned short* Kb  = (unsigned short*)(ws + ((size_t)24 << 20)); // 8 MB K [bh,s,d]
  unsigned short* Vb  = (unsigned short*)(ws + ((size_t)32 << 20)); // 8 MB V [bh,s,d]
  unsigned short* Vtb = (unsigned short*)(ws + ((size_t)40 << 20)); // 8 MB V^T [bh,d,s]

  cvt_all_k<<<(N4_X + N4_WQ + N4_WO) / 256, 256, 0, stream>>>(x, W_qkv, W_out, xb, wqb, wob);

  gemm_bt<1, 3072, 1024><<<dim3(32, 24), 256, 0, stream>>>(xb, wqb, b_qkv, nullptr, Qb, Kb, Vb);
  transpose_v_k<<<dim3(32, 32), 256, 0, stream>>>(Vb, Vtb);
  attn_fwd<<<dim3(32, 32), 128, 0, stream>>>(Qb, Kb, Vtb, AOb);
  gemm_bt<0, 1024, 1024><<<dim3(32, 8), 256, 0, stream>>>(AOb, wob, b_out, out, nullptr, nullptr, nullptr);
}